// Round 1
// 212.019 us; speedup vs baseline: 1.0301x; 1.0301x over previous
//
#include <hip/hip_runtime.h>

// Problem constants
#define TB 2
#define TT 2048
#define TE 1024
#define TH 16
#define THS 64
#define TM (TB * TT)  // 4096

typedef __attribute__((ext_vector_type(8))) short short8;   // 8 x bf16 (4 VGPRs)
typedef __attribute__((ext_vector_type(4))) float f32x4;    // MFMA accumulator

__device__ __forceinline__ f32x4 mfma16(short8 a, short8 b, f32x4 c) {
    return __builtin_amdgcn_mfma_f32_16x16x32_bf16(a, b, c, 0, 0, 0);
}

// async global->LDS, 16B per lane; LDS dest = wave-uniform base + lane*16
__device__ __forceinline__ void gload_lds16(const void* g, void* l) {
    __builtin_amdgcn_global_load_lds(
        (const __attribute__((address_space(1))) void*)g,
        (__attribute__((address_space(3))) void*)l, 16, 0, 0);
}

__device__ __forceinline__ unsigned short f2bf(float f) {
    unsigned int u = __float_as_uint(f);
    u += 0x7fff + ((u >> 16) & 1);  // RNE
    return (unsigned short)(u >> 16);
}

// ---------------------------------------------------------------------------
// fp32 -> bf16 cast for q,k,v in one launch: grid (n4/256, 3)
// ---------------------------------------------------------------------------
__global__ __launch_bounds__(256) void cast3_f32_bf16(
    const float* __restrict__ a, const float* __restrict__ b,
    const float* __restrict__ c, unsigned short* __restrict__ oa,
    unsigned short* __restrict__ ob, unsigned short* __restrict__ oc, int n4) {
    const float* src = (blockIdx.y == 0) ? a : (blockIdx.y == 1) ? b : c;
    unsigned short* dst = (blockIdx.y == 0) ? oa : (blockIdx.y == 1) ? ob : oc;
    int i = blockIdx.x * 256 + threadIdx.x;
    if (i < n4) {
        float4 v = ((const float4*)src)[i];
        ushort4 o;
        o.x = f2bf(v.x); o.y = f2bf(v.y); o.z = f2bf(v.z); o.w = f2bf(v.w);
        ((ushort4*)dst)[i] = o;
    }
}

// ---------------------------------------------------------------------------
// W [K][N] fp32 -> Wt [N][K] bf16, all 4 weights in one launch: grid (32,32,4)
// ---------------------------------------------------------------------------
__global__ __launch_bounds__(256) void transpose_cast_w4(
    const float* __restrict__ W0, const float* __restrict__ W1,
    const float* __restrict__ W2, const float* __restrict__ W3,
    unsigned short* __restrict__ T0, unsigned short* __restrict__ T1,
    unsigned short* __restrict__ T2, unsigned short* __restrict__ T3) {
    __shared__ float Ts[32][33];
    const int z = blockIdx.z;
    const float* W = (z == 0) ? W0 : (z == 1) ? W1 : (z == 2) ? W2 : W3;
    unsigned short* Wt = (z == 0) ? T0 : (z == 1) ? T1 : (z == 2) ? T2 : T3;
    const int r0 = blockIdx.y * 32, c0 = blockIdx.x * 32;
    const int t = threadIdx.x;
    const int r = t >> 3, c = (t & 7) * 4;
    float4 v = *(const float4*)&W[(size_t)(r0 + r) * TE + c0 + c];
    Ts[r][c] = v.x; Ts[r][c + 1] = v.y; Ts[r][c + 2] = v.z; Ts[r][c + 3] = v.w;
    __syncthreads();
    ushort4 o;
    o.x = f2bf(Ts[c + 0][r]); o.y = f2bf(Ts[c + 1][r]);
    o.z = f2bf(Ts[c + 2][r]); o.w = f2bf(Ts[c + 3][r]);
    *(ushort4*)&Wt[(size_t)(c0 + r) * TE + r0 + c] = o;
}

// ---------------------------------------------------------------------------
// Fused QKV GEMM, R9: m97 structure. BM=128, BN=128, BK=32, grid (32,8,3).
// 4 waves, each owns a 64x64 sub-tile -> 16 MFMA per K-step per wave
// (vs 8 before), 8 ds_read_b128, 4 global_load_lds. Same zero-conflict
// XOR swizzle as before, extended to 8 A-chunks + 8 B-chunks.
// ---------------------------------------------------------------------------
__global__ __launch_bounds__(256, 2) void gemm_qkv(
    const unsigned short* __restrict__ qc, const unsigned short* __restrict__ kc,
    const unsigned short* __restrict__ vc, const unsigned short* __restrict__ Wqt,
    const unsigned short* __restrict__ Wkt, const unsigned short* __restrict__ Wvt,
    unsigned short* __restrict__ Qb, unsigned short* __restrict__ Kb,
    unsigned short* __restrict__ Vt) {
    __shared__ unsigned short As[2][128 * 32];   // 8 KB per buf
    __shared__ unsigned short Bs[2][128 * 32];   // 8 KB per buf

    const int z = blockIdx.z;
    const unsigned short* A  = (z == 0) ? qc : (z == 1) ? kc : vc;
    const unsigned short* Bt = (z == 0) ? Wqt : (z == 1) ? Wkt : Wvt;

    const int tid = threadIdx.x;
    const int w = tid >> 6, lane = tid & 63;
    const int quad = lane >> 4, l16 = lane & 15;
    const int bm = blockIdx.x * 128, bn = blockIdx.y * 128;
    const int wm = (w >> 1) * 64, wn = (w & 1) * 64;

    f32x4 acc[4][4];
    const f32x4 fz = {0.f, 0.f, 0.f, 0.f};
    #pragma unroll
    for (int i = 0; i < 4; ++i)
        #pragma unroll
        for (int j = 0; j < 4; ++j) acc[i][j] = fz;

    const int srow = lane >> 2;
    const int scol = (((lane & 3) ^ ((srow >> 1) & 3))) * 8;  // swizzled source col
    const int rchunk = (quad ^ ((l16 >> 1) & 3)) * 8;          // swizzled read col

    auto stage = [&](int k0, int buf) {
        #pragma unroll
        for (int i = 0; i < 4; ++i) {               // 16 chunks over 4 waves
            const int ch = w * 4 + i;
            if (ch < 8)
                gload_lds16(A + (size_t)(bm + ch * 16 + srow) * TE + k0 + scol,
                            &As[buf][ch * 512 + lane * 8]);
            else
                gload_lds16(Bt + (size_t)(bn + (ch - 8) * 16 + srow) * TE + k0 + scol,
                            &Bs[buf][(ch - 8) * 512 + lane * 8]);
        }
    };

    stage(0, 0);
    int cur = 0;
    for (int k0 = 0; k0 < TE; k0 += 32) {
        __syncthreads();
        if (k0 + 32 < TE) stage(k0 + 32, cur ^ 1);

        short8 af[4], bf[4];
        #pragma unroll
        for (int i = 0; i < 4; ++i)
            af[i] = *(const short8*)&As[cur][(wm + i * 16 + l16) * 32 + rchunk];
        #pragma unroll
        for (int j = 0; j < 4; ++j)
            bf[j] = *(const short8*)&Bs[cur][(wn + j * 16 + l16) * 32 + rchunk];
        #pragma unroll
        for (int i = 0; i < 4; ++i)
            #pragma unroll
            for (int j = 0; j < 4; ++j)
                acc[i][j] = mfma16(af[i], bf[j], acc[i][j]);
        cur ^= 1;
    }

    if (z < 2) {
        unsigned short* Cb = (z == 0) ? Qb : Kb;
        #pragma unroll
        for (int i = 0; i < 4; ++i)
            #pragma unroll
            for (int j = 0; j < 4; ++j) {
                const int m0 = bm + wm + i * 16 + quad * 4;
                const int n = bn + wn + j * 16 + l16;
                #pragma unroll
                for (int r = 0; r < 4; ++r)
                    Cb[(size_t)(m0 + r) * TE + n] = f2bf(acc[i][j][r]);
            }
    } else {
        // V^T: Vt[((b*H + h)*HS + d)*T + t]
        #pragma unroll
        for (int i = 0; i < 4; ++i)
            #pragma unroll
            for (int j = 0; j < 4; ++j) {
                const int m0 = bm + wm + i * 16 + quad * 4;
                const int n = bn + wn + j * 16 + l16;
                ushort4 o;
                o.x = f2bf(acc[i][j][0]); o.y = f2bf(acc[i][j][1]);
                o.z = f2bf(acc[i][j][2]); o.w = f2bf(acc[i][j][3]);
                size_t idx = ((size_t)((m0 >> 11) * TH + (n >> 6)) * THS + (n & 63)) * TT + (m0 & (TT - 1));
                *(ushort4*)&Vt[idx] = o;
            }
    }
}

// ---------------------------------------------------------------------------
// Output projection GEMM, R9: BM=128, BN=64, grid (32,16) = 512 blocks.
// Each wave owns 64x32 -> 8 MFMA per K-step (vs 4 before).
// ---------------------------------------------------------------------------
__global__ __launch_bounds__(256, 2) void gemm_out(
    const unsigned short* __restrict__ A, const unsigned short* __restrict__ Bt,
    float* __restrict__ C) {
    __shared__ unsigned short As[2][128 * 32];   // 8 KB per buf
    __shared__ unsigned short Bs[2][64 * 32];    // 4 KB per buf

    const int tid = threadIdx.x;
    const int w = tid >> 6, lane = tid & 63;
    const int quad = lane >> 4, l16 = lane & 15;
    const int bm = blockIdx.x * 128, bn = blockIdx.y * 64;
    const int wm = (w >> 1) * 64, wn = (w & 1) * 32;

    f32x4 acc[4][2];
    const f32x4 fz = {0.f, 0.f, 0.f, 0.f};
    #pragma unroll
    for (int i = 0; i < 4; ++i)
        #pragma unroll
        for (int j = 0; j < 2; ++j) acc[i][j] = fz;

    const int srow = lane >> 2;
    const int scol = (((lane & 3) ^ ((srow >> 1) & 3))) * 8;
    const int rchunk = (quad ^ ((l16 >> 1) & 3)) * 8;

    auto stage = [&](int k0, int buf) {
        #pragma unroll
        for (int i = 0; i < 3; ++i) {               // 12 chunks over 4 waves
            const int ch = w * 3 + i;
            if (ch < 8)
                gload_lds16(A + (size_t)(bm + ch * 16 + srow) * TE + k0 + scol,
                            &As[buf][ch * 512 + lane * 8]);
            else
                gload_lds16(Bt + (size_t)(bn + (ch - 8) * 16 + srow) * TE + k0 + scol,
                            &Bs[buf][(ch - 8) * 512 + lane * 8]);
        }
    };

    stage(0, 0);
    int cur = 0;
    for (int k0 = 0; k0 < TE; k0 += 32) {
        __syncthreads();
        if (k0 + 32 < TE) stage(k0 + 32, cur ^ 1);

        short8 af[4], bf[2];
        #pragma unroll
        for (int i = 0; i < 4; ++i)
            af[i] = *(const short8*)&As[cur][(wm + i * 16 + l16) * 32 + rchunk];
        #pragma unroll
        for (int j = 0; j < 2; ++j)
            bf[j] = *(const short8*)&Bs[cur][(wn + j * 16 + l16) * 32 + rchunk];
        #pragma unroll
        for (int i = 0; i < 4; ++i)
            #pragma unroll
            for (int j = 0; j < 2; ++j)
                acc[i][j] = mfma16(af[i], bf[j], acc[i][j]);
        cur ^= 1;
    }

    #pragma unroll
    for (int i = 0; i < 4; ++i)
        #pragma unroll
        for (int j = 0; j < 2; ++j) {
            const int m0 = bm + wm + i * 16 + quad * 4;
            const int n = bn + wn + j * 16 + l16;
            #pragma unroll
            for (int r = 0; r < 4; ++r)
                C[(size_t)(m0 + r) * TE + n] = acc[i][j][r];
        }
}

// ---------------------------------------------------------------------------
// Flash attention, bf16 MFMA, S^T = K·Q^T, no online max (partials additive!).
//  * 512 threads = 2 K-split wave-groups x 4 waves. Group wk processes key
//    tiles jt in [wk?h0:0 , ...) where h0 = ceil((it+1)/2); O and l partials
//    are ADDITIVE (fixed max=0), combined intra-block through the freed K
//    double-buffer slots in LDS. Dead (padding) iterations are masked via
//    lim -> exp2(-1e30) = 0 and restage a clamped tile (no OOB).
//  * With q-tile pairing (p -> tiles 31-p and p), EVERY block runs exactly
//    17 loop iterations: 512 uniform blocks, 2/CU, 16 waves/CU.
//  * XCD-swizzled 1-D grid: bh = (lin&7)*4 + ((lin>>3)&3), p = lin>>5 puts
//    all 16 blocks of one (b,h) on one XCD -> K/V (2MB/4 heads) stays in L2.
// Q,K: [B*T][E] bf16. Vt: [B][H][HS][T] bf16. O: [B*T][E] bf16.
// ---------------------------------------------------------------------------
__global__ __launch_bounds__(512, 4) void attn_mfma(
    const unsigned short* __restrict__ Q, const unsigned short* __restrict__ K,
    const unsigned short* __restrict__ Vt, unsigned short* __restrict__ O) {
    // per group (wk): K buf0 | K buf1 | V buf0 | V buf1, each 4096 ush (8KB)
    __shared__ unsigned short S[2][16384];   // 64 KB
    __shared__ float L0[64];

    const int tid = threadIdx.x;
    const int lane = tid & 63;
    const int wv = tid >> 6;          // 0..7
    const int wk = wv >> 2;           // K-split group
    const int wl = wv & 3;            // wave within group
    const int quad = lane >> 4, l16 = lane & 15;

    const int lin = blockIdx.x;
    const int bh = (lin & 7) * 4 + ((lin >> 3) & 3);  // XCD-pinned head
    const int p = lin >> 5;                            // pair index 0..15
    const int b = bh >> 4, h = bh & 15;
    const int itA = (TT / 64) - 1 - p;                 // heavy q-tile
    const int itB = p;                                 // light q-tile

    const unsigned short* Kg = K + (size_t)b * TT * TE + h * THS;  // row stride TE
    const unsigned short* Vg = Vt + (size_t)bh * THS * TT;         // [d][t]

    // Q fragments for both segments (A/B MFMA operand layouts coincide)
    const size_t qrA = (size_t)(b * TT + itA * 64 + wl * 16 + l16) * TE + h * THS;
    const size_t qrB = (size_t)(b * TT + itB * 64 + wl * 16 + l16) * TE + h * THS;
    const short8 aqA0 = *(const short8*)&Q[qrA + quad * 8];
    const short8 aqA1 = *(const short8*)&Q[qrA + 32 + quad * 8];
    const short8 aqB0 = *(const short8*)&Q[qrB + quad * 8];
    const short8 aqB1 = *(const short8*)&Q[qrB + 32 + quad * 8];

    const f32x4 fz = {0.f, 0.f, 0.f, 0.f};
    const int srow = lane >> 2;
    const int scol = (((lane & 3) ^ ((srow >> 1) & 3))) * 8;  // swizzled source col
    const int rchunk = (quad ^ ((l16 >> 1) & 3)) * 8;          // swizzled read col

    unsigned short* Sw = S[wk];
    float* Sf = (float*)S;

    auto stageKV = [&](int jt, int it, int buf) {
        const int k0 = (jt > it ? it : jt) * 64;   // clamp dead iterations
        if (wl < 2) {  // waves 0-1 of group: K tile (8 KB)
            #pragma unroll
            for (int j = 0; j < 4; ++j) {
                const int ee = wl * 4 + j;
                const int kk = ee >> 2, r16 = (ee & 3) * 16;
                gload_lds16(Kg + (size_t)(k0 + r16 + srow) * TE + kk * 32 + scol,
                            &Sw[buf * 4096 + ee * 512 + lane * 8]);
            }
        } else {       // waves 2-3 of group: V^T tile (8 KB)
            #pragma unroll
            for (int j = 0; j < 4; ++j) {
                const int ee = (wl - 2) * 4 + j;
                const int kk = ee >> 2, r16 = (ee & 3) * 16;
                gload_lds16(Vg + (size_t)(r16 + srow) * TT + k0 + kk * 32 + scol,
                            &Sw[8192 + buf * 4096 + ee * 512 + lane * 8]);
            }
        }
    };

    int cur = 0;
    const float SC = 0.18033688011112042f;  // 0.125 * log2(e)
    const int src0 = ((quad & 1) << 5) + l16;
    const bool hi = quad >= 2;

    auto segment = [&](int it, short8 aq0, short8 aq1, int nextit /* -1 = none */) {
        const int h0 = (it + 2) >> 1;          // ceil((it+1)/2), loop count (both groups)
        const int base = wk ? h0 : 0;
        f32x4 acc_o[4];
        #pragma unroll
        for (int ni = 0; ni < 4; ++ni) acc_o[ni] = fz;
        float lacc = 0.f;
        const int q0 = it * 64;
        const int qg = q0 + wl * 16 + l16;     // this lane's q column (S^T)

        for (int i = 0; i < h0; ++i) {
            const int jt = base + i;
            __syncthreads();                   // buf[cur] staged; buf[cur^1] free
            if (i + 1 < h0) stageKV(base + i + 1, it, cur ^ 1);
            else if (nextit >= 0) stageKV(wk ? ((nextit + 2) >> 1) : 0, nextit, cur ^ 1);

            // S^T = K·Q^T
            f32x4 s[4];
            #pragma unroll
            for (int ni = 0; ni < 4; ++ni) {
                short8 kf0 = *(const short8*)&Sw[cur * 4096 + (ni * 16 + l16) * 32 + rchunk];
                short8 kf1 = *(const short8*)&Sw[cur * 4096 + 2048 + (ni * 16 + l16) * 32 + rchunk];
                s[ni] = mfma16(kf0, aq0, fz);
                s[ni] = mfma16(kf1, aq1, s[ni]);
            }

            // softmax weights (fixed max=0), exp2 domain; lim handles
            // off-diagonal / diagonal / dead-iteration in one path
            const int k0 = jt * 64;
            const int lim = (jt < it) ? 0x7fffffff : ((jt == it) ? qg : -0x7fffffff);
            float pv[4][4];
            #pragma unroll
            for (int ni = 0; ni < 4; ++ni) {
                const int kpb = k0 + ni * 16 + quad * 4;
                #pragma unroll
                for (int r = 0; r < 4; ++r) {
                    float sv = (kpb + r > lim) ? -1e30f : s[ni][r] * SC;
                    pv[ni][r] = __builtin_amdgcn_exp2f(sv);
                    lacc += pv[ni][r];
                }
            }

            // pack P^T: pd0[t]=(r0,r1), pd1[t]=(r2,r3)
            unsigned int pd0[4], pd1[4];
            #pragma unroll
            for (int t = 0; t < 4; ++t) {
                pd0[t] = (unsigned)f2bf(pv[t][0]) | ((unsigned)f2bf(pv[t][1]) << 16);
                pd1[t] = (unsigned)f2bf(pv[t][2]) | ((unsigned)f2bf(pv[t][3]) << 16);
            }

            // C->A transform via shuffles (no LDS)
            short8 pf[2];
            #pragma unroll
            for (int c = 0; c < 2; ++c) {
                const int tl = 2 * c, th = 2 * c + 1;
                unsigned d0l = __shfl(pd0[tl], src0),      d0h = __shfl(pd0[th], src0);
                unsigned d1l = __shfl(pd1[tl], src0),      d1h = __shfl(pd1[th], src0);
                unsigned d2l = __shfl(pd0[tl], src0 + 16), d2h = __shfl(pd0[th], src0 + 16);
                unsigned d3l = __shfl(pd1[tl], src0 + 16), d3h = __shfl(pd1[th], src0 + 16);
                union { unsigned u[4]; short8 s8; } pk;
                pk.u[0] = hi ? d0h : d0l;
                pk.u[1] = hi ? d1h : d1l;
                pk.u[2] = hi ? d2h : d2l;
                pk.u[3] = hi ? d3h : d3l;
                pf[c] = pk.s8;
            }

            // O += P·V
            #pragma unroll
            for (int ni = 0; ni < 4; ++ni) {
                short8 v0 = *(const short8*)&Sw[8192 + cur * 4096 + (ni * 16 + l16) * 32 + rchunk];
                short8 v1 = *(const short8*)&Sw[8192 + cur * 4096 + 2048 + (ni * 16 + l16) * 32 + rchunk];
                acc_o[ni] = mfma16(pf[0], v0, acc_o[ni]);
                acc_o[ni] = mfma16(pf[1], v1, acc_o[ni]);
            }
            cur ^= 1;
        }

        // full column sums within group
        lacc += __shfl_xor(lacc, 16);
        lacc += __shfl_xor(lacc, 32);

        // cross-group combine through freed K buffers (buf cur^1 of each group)
        __syncthreads();                        // all reads of freed bufs done
        const int fb = cur ^ 1;
        if (wk == 0) {
            #pragma unroll
            for (int ni = 0; ni < 4; ++ni)
                #pragma unroll
                for (int r = 0; r < 4; ++r) {
                    const int row = wl * 16 + quad * 4 + r;
                    const int idx = row * 64 + ni * 16 + l16;
                    Sf[(idx >> 11) * 8192 + fb * 2048 + (idx & 2047)] = acc_o[ni][r];
                }
            if (quad == 0) L0[wl * 16 + l16] = lacc;
        }
        __syncthreads();
        if (wk == 1) {
            const float lf = lacc + L0[wl * 16 + l16];
            float linv[4];
            #pragma unroll
            for (int r = 0; r < 4; ++r)
                linv[r] = 1.0f / __shfl(lf, quad * 4 + r);
            unsigned short* Og = O + (size_t)(b * TT + q0 + wl * 16 + quad * 4) * TE + h * THS;
            #pragma unroll
            for (int r = 0; r < 4; ++r)
                #pragma unroll
                for (int ni = 0; ni < 4; ++ni) {
                    const int row = wl * 16 + quad * 4 + r;
                    const int idx = row * 64 + ni * 16 + l16;
                    const float o = acc_o[ni][r] + Sf[(idx >> 11) * 8192 + fb * 2048 + (idx & 2047)];
                    Og[(size_t)r * TE + ni * 16 + l16] = f2bf(o * linv[r]);
                }
        }
    };

    // initial stage: each group its own first tile of segment A
    stageKV(wk ? ((itA + 2) >> 1) : 0, itA, 0);
    segment(itA, aqA0, aqA1, itB);   // heavy tile; last iter prefetches B
    segment(itB, aqB0, aqB1, -1);    // light tile
}

// ---------------------------------------------------------------------------
// Orchestration. Workspace (64 MiB):
//   qc,kc,vc,Qb,Kb,Vt,Ob: 7 x 8 MiB bf16; Wqt,Wkt,Wvt,Wpt: 4 x 2 MiB bf16
// ---------------------------------------------------------------------------
extern "C" void kernel_launch(void* const* d_in, const int* in_sizes, int n_in,
                              void* d_out, int out_size, void* d_ws, size_t ws_size,
                              hipStream_t stream) {
    const float* q  = (const float*)d_in[0];
    const float* k  = (const float*)d_in[1];
    const float* v  = (const float*)d_in[2];
    const float* Wq = (const float*)d_in[3];
    const float* Wk = (const float*)d_in[4];
    const float* Wv = (const float*)d_in[5];
    const float* Wp = (const float*)d_in[6];
    float* out = (float*)d_out;

    const size_t se = (size_t)TM * TE;  // 4,194,304
    unsigned short* qc  = (unsigned short*)d_ws;
    unsigned short* kc  = qc + se;
    unsigned short* vc  = kc + se;
    unsigned short* Qb  = vc + se;
    unsigned short* Kb  = Qb + se;
    unsigned short* Vt  = Kb + se;
    unsigned short* Ob  = Vt + se;
    unsigned short* Wqt = Ob + se;
    unsigned short* Wkt = Wqt + (size_t)TE * TE;
    unsigned short* Wvt = Wkt + (size_t)TE * TE;
    unsigned short* Wpt = Wvt + (size_t)TE * TE;

    const int n4 = (int)(se / 4);
    cast3_f32_bf16<<<dim3(n4 / 256, 3), 256, 0, stream>>>(q, k, v, qc, kc, vc, n4);
    transpose_cast_w4<<<dim3(TE / 32, TE / 32, 4), 256, 0, stream>>>(
        Wq, Wk, Wv, Wp, Wqt, Wkt, Wvt, Wpt);

    gemm_qkv<<<dim3(TM / 128, TE / 128, 3), 256, 0, stream>>>(
        qc, kc, vc, Wqt, Wkt, Wvt, Qb, Kb, Vt);

    attn_mfma<<<512, 512, 0, stream>>>(Qb, Kb, Vt, Ob);

    gemm_out<<<dim3(TM / 128, TE / 64), 256, 0, stream>>>(Ob, Wpt, out);
}

// Round 2
// 201.909 us; speedup vs baseline: 1.0817x; 1.0501x over previous
//
#include <hip/hip_runtime.h>

// Problem constants
#define TB 2
#define TT 2048
#define TE 1024
#define TH 16
#define THS 64
#define TM (TB * TT)  // 4096

typedef __attribute__((ext_vector_type(8))) short short8;   // 8 x bf16 (4 VGPRs)
typedef __attribute__((ext_vector_type(4))) float f32x4;    // MFMA accumulator

__device__ __forceinline__ f32x4 mfma16(short8 a, short8 b, f32x4 c) {
    return __builtin_amdgcn_mfma_f32_16x16x32_bf16(a, b, c, 0, 0, 0);
}

// async global->LDS, 16B per lane; LDS dest = wave-uniform base + lane*16
__device__ __forceinline__ void gload_lds16(const void* g, void* l) {
    __builtin_amdgcn_global_load_lds(
        (const __attribute__((address_space(1))) void*)g,
        (__attribute__((address_space(3))) void*)l, 16, 0, 0);
}

__device__ __forceinline__ unsigned short f2bf(float f) {
    unsigned int u = __float_as_uint(f);
    u += 0x7fff + ((u >> 16) & 1);  // RNE
    return (unsigned short)(u >> 16);
}

// HW packed f32x2 -> bf16x2, RNE (T12 recipe; no builtin on gfx950)
__device__ __forceinline__ unsigned cvtpk_bf16(float lo, float hi) {
    unsigned r;
    asm("v_cvt_pk_bf16_f32 %0, %1, %2" : "=v"(r) : "v"(lo), "v"(hi));
    return r;
}

// ---------------------------------------------------------------------------
// fp32 -> bf16 cast for q,k,v in one launch: grid (n4/256, 3)
// ---------------------------------------------------------------------------
__global__ __launch_bounds__(256) void cast3_f32_bf16(
    const float* __restrict__ a, const float* __restrict__ b,
    const float* __restrict__ c, unsigned short* __restrict__ oa,
    unsigned short* __restrict__ ob, unsigned short* __restrict__ oc, int n4) {
    const float* src = (blockIdx.y == 0) ? a : (blockIdx.y == 1) ? b : c;
    unsigned short* dst = (blockIdx.y == 0) ? oa : (blockIdx.y == 1) ? ob : oc;
    int i = blockIdx.x * 256 + threadIdx.x;
    if (i < n4) {
        float4 v = ((const float4*)src)[i];
        ushort4 o;
        o.x = f2bf(v.x); o.y = f2bf(v.y); o.z = f2bf(v.z); o.w = f2bf(v.w);
        ((ushort4*)dst)[i] = o;
    }
}

// ---------------------------------------------------------------------------
// W [K][N] fp32 -> Wt [N][K] bf16, all 4 weights in one launch: grid (32,32,4)
// ---------------------------------------------------------------------------
__global__ __launch_bounds__(256) void transpose_cast_w4(
    const float* __restrict__ W0, const float* __restrict__ W1,
    const float* __restrict__ W2, const float* __restrict__ W3,
    unsigned short* __restrict__ T0, unsigned short* __restrict__ T1,
    unsigned short* __restrict__ T2, unsigned short* __restrict__ T3) {
    __shared__ float Ts[32][33];
    const int z = blockIdx.z;
    const float* W = (z == 0) ? W0 : (z == 1) ? W1 : (z == 2) ? W2 : W3;
    unsigned short* Wt = (z == 0) ? T0 : (z == 1) ? T1 : (z == 2) ? T2 : T3;
    const int r0 = blockIdx.y * 32, c0 = blockIdx.x * 32;
    const int t = threadIdx.x;
    const int r = t >> 3, c = (t & 7) * 4;
    float4 v = *(const float4*)&W[(size_t)(r0 + r) * TE + c0 + c];
    Ts[r][c] = v.x; Ts[r][c + 1] = v.y; Ts[r][c + 2] = v.z; Ts[r][c + 3] = v.w;
    __syncthreads();
    ushort4 o;
    o.x = f2bf(Ts[c + 0][r]); o.y = f2bf(Ts[c + 1][r]);
    o.z = f2bf(Ts[c + 2][r]); o.w = f2bf(Ts[c + 3][r]);
    *(ushort4*)&Wt[(size_t)(c0 + r) * TE + r0 + c] = o;
}

// ---------------------------------------------------------------------------
// Fused QKV GEMM: BM=128, BN=128, BK=32, grid (32,8,3), m97 structure.
// NEW R10: z==0 (Q) epilogue pre-scales by 0.125*log2(e) so the attention
// hot loop computes exp2(s) with no per-element multiply.
// ---------------------------------------------------------------------------
__global__ __launch_bounds__(256, 2) void gemm_qkv(
    const unsigned short* __restrict__ qc, const unsigned short* __restrict__ kc,
    const unsigned short* __restrict__ vc, const unsigned short* __restrict__ Wqt,
    const unsigned short* __restrict__ Wkt, const unsigned short* __restrict__ Wvt,
    unsigned short* __restrict__ Qb, unsigned short* __restrict__ Kb,
    unsigned short* __restrict__ Vt) {
    __shared__ unsigned short As[2][128 * 32];   // 8 KB per buf
    __shared__ unsigned short Bs[2][128 * 32];   // 8 KB per buf

    const int z = blockIdx.z;
    const unsigned short* A  = (z == 0) ? qc : (z == 1) ? kc : vc;
    const unsigned short* Bt = (z == 0) ? Wqt : (z == 1) ? Wkt : Wvt;

    const int tid = threadIdx.x;
    const int w = tid >> 6, lane = tid & 63;
    const int quad = lane >> 4, l16 = lane & 15;
    const int bm = blockIdx.x * 128, bn = blockIdx.y * 128;
    const int wm = (w >> 1) * 64, wn = (w & 1) * 64;

    f32x4 acc[4][4];
    const f32x4 fz = {0.f, 0.f, 0.f, 0.f};
    #pragma unroll
    for (int i = 0; i < 4; ++i)
        #pragma unroll
        for (int j = 0; j < 4; ++j) acc[i][j] = fz;

    const int srow = lane >> 2;
    const int scol = (((lane & 3) ^ ((srow >> 1) & 3))) * 8;  // swizzled source col
    const int rchunk = (quad ^ ((l16 >> 1) & 3)) * 8;          // swizzled read col

    auto stage = [&](int k0, int buf) {
        #pragma unroll
        for (int i = 0; i < 4; ++i) {               // 16 chunks over 4 waves
            const int ch = w * 4 + i;
            if (ch < 8)
                gload_lds16(A + (size_t)(bm + ch * 16 + srow) * TE + k0 + scol,
                            &As[buf][ch * 512 + lane * 8]);
            else
                gload_lds16(Bt + (size_t)(bn + (ch - 8) * 16 + srow) * TE + k0 + scol,
                            &Bs[buf][(ch - 8) * 512 + lane * 8]);
        }
    };

    stage(0, 0);
    int cur = 0;
    for (int k0 = 0; k0 < TE; k0 += 32) {
        __syncthreads();
        if (k0 + 32 < TE) stage(k0 + 32, cur ^ 1);

        short8 af[4], bf[4];
        #pragma unroll
        for (int i = 0; i < 4; ++i)
            af[i] = *(const short8*)&As[cur][(wm + i * 16 + l16) * 32 + rchunk];
        #pragma unroll
        for (int j = 0; j < 4; ++j)
            bf[j] = *(const short8*)&Bs[cur][(wn + j * 16 + l16) * 32 + rchunk];
        #pragma unroll
        for (int i = 0; i < 4; ++i)
            #pragma unroll
            for (int j = 0; j < 4; ++j)
                acc[i][j] = mfma16(af[i], bf[j], acc[i][j]);
        cur ^= 1;
    }

    if (z < 2) {
        unsigned short* Cb = (z == 0) ? Qb : Kb;
        const float sc = (z == 0) ? 0.18033688011112042f : 1.0f;  // 0.125*log2(e)
        #pragma unroll
        for (int i = 0; i < 4; ++i)
            #pragma unroll
            for (int j = 0; j < 4; ++j) {
                const int m0 = bm + wm + i * 16 + quad * 4;
                const int n = bn + wn + j * 16 + l16;
                #pragma unroll
                for (int r = 0; r < 4; ++r)
                    Cb[(size_t)(m0 + r) * TE + n] = f2bf(acc[i][j][r] * sc);
            }
    } else {
        // V^T: Vt[((b*H + h)*HS + d)*T + t]
        #pragma unroll
        for (int i = 0; i < 4; ++i)
            #pragma unroll
            for (int j = 0; j < 4; ++j) {
                const int m0 = bm + wm + i * 16 + quad * 4;
                const int n = bn + wn + j * 16 + l16;
                ushort4 o;
                o.x = f2bf(acc[i][j][0]); o.y = f2bf(acc[i][j][1]);
                o.z = f2bf(acc[i][j][2]); o.w = f2bf(acc[i][j][3]);
                size_t idx = ((size_t)((m0 >> 11) * TH + (n >> 6)) * THS + (n & 63)) * TT + (m0 & (TT - 1));
                *(ushort4*)&Vt[idx] = o;
            }
    }
}

// ---------------------------------------------------------------------------
// Output projection GEMM: BM=128, BN=64, grid (32,16) = 512 blocks.
// ---------------------------------------------------------------------------
__global__ __launch_bounds__(256, 2) void gemm_out(
    const unsigned short* __restrict__ A, const unsigned short* __restrict__ Bt,
    float* __restrict__ C) {
    __shared__ unsigned short As[2][128 * 32];   // 8 KB per buf
    __shared__ unsigned short Bs[2][64 * 32];    // 4 KB per buf

    const int tid = threadIdx.x;
    const int w = tid >> 6, lane = tid & 63;
    const int quad = lane >> 4, l16 = lane & 15;
    const int bm = blockIdx.x * 128, bn = blockIdx.y * 64;
    const int wm = (w >> 1) * 64, wn = (w & 1) * 32;

    f32x4 acc[4][2];
    const f32x4 fz = {0.f, 0.f, 0.f, 0.f};
    #pragma unroll
    for (int i = 0; i < 4; ++i)
        #pragma unroll
        for (int j = 0; j < 2; ++j) acc[i][j] = fz;

    const int srow = lane >> 2;
    const int scol = (((lane & 3) ^ ((srow >> 1) & 3))) * 8;
    const int rchunk = (quad ^ ((l16 >> 1) & 3)) * 8;

    auto stage = [&](int k0, int buf) {
        #pragma unroll
        for (int i = 0; i < 3; ++i) {               // 12 chunks over 4 waves
            const int ch = w * 3 + i;
            if (ch < 8)
                gload_lds16(A + (size_t)(bm + ch * 16 + srow) * TE + k0 + scol,
                            &As[buf][ch * 512 + lane * 8]);
            else
                gload_lds16(Bt + (size_t)(bn + (ch - 8) * 16 + srow) * TE + k0 + scol,
                            &Bs[buf][(ch - 8) * 512 + lane * 8]);
        }
    };

    stage(0, 0);
    int cur = 0;
    for (int k0 = 0; k0 < TE; k0 += 32) {
        __syncthreads();
        if (k0 + 32 < TE) stage(k0 + 32, cur ^ 1);

        short8 af[4], bf[2];
        #pragma unroll
        for (int i = 0; i < 4; ++i)
            af[i] = *(const short8*)&As[cur][(wm + i * 16 + l16) * 32 + rchunk];
        #pragma unroll
        for (int j = 0; j < 2; ++j)
            bf[j] = *(const short8*)&Bs[cur][(wn + j * 16 + l16) * 32 + rchunk];
        #pragma unroll
        for (int i = 0; i < 4; ++i)
            #pragma unroll
            for (int j = 0; j < 2; ++j)
                acc[i][j] = mfma16(af[i], bf[j], acc[i][j]);
        cur ^= 1;
    }

    #pragma unroll
    for (int i = 0; i < 4; ++i)
        #pragma unroll
        for (int j = 0; j < 2; ++j) {
            const int m0 = bm + wm + i * 16 + quad * 4;
            const int n = bn + wn + j * 16 + l16;
            #pragma unroll
            for (int r = 0; r < 4; ++r)
                C[(size_t)(m0 + r) * TE + n] = acc[i][j][r];
        }
}

// ---------------------------------------------------------------------------
// Flash attention, bf16 MFMA, S^T = K·Q^T, no online max (partials additive!).
// R10 VALU diet: Q pre-scaled (no per-element mul), tile-type-specialized
// masking (off-diag tiles skip cmp/sel entirely; dead iters skip exp2),
// v_cvt_pk_bf16_f32 packing (1 inst per 2 elements vs ~6 VALU/element).
// Q,K: [B*T][E] bf16 (Q pre-scaled by 0.125*log2e). Vt: [B][H][HS][T] bf16.
// ---------------------------------------------------------------------------
__global__ __launch_bounds__(512, 4) void attn_mfma(
    const unsigned short* __restrict__ Q, const unsigned short* __restrict__ K,
    const unsigned short* __restrict__ Vt, unsigned short* __restrict__ O) {
    // per group (wk): K buf0 | K buf1 | V buf0 | V buf1, each 4096 ush (8KB)
    __shared__ unsigned short S[2][16384];   // 64 KB
    __shared__ float L0[64];

    const int tid = threadIdx.x;
    const int lane = tid & 63;
    const int wv = tid >> 6;          // 0..7
    const int wk = wv >> 2;           // K-split group
    const int wl = wv & 3;            // wave within group
    const int quad = lane >> 4, l16 = lane & 15;

    const int lin = blockIdx.x;
    const int bh = (lin & 7) * 4 + ((lin >> 3) & 3);  // XCD-pinned head
    const int p = lin >> 5;                            // pair index 0..15
    const int b = bh >> 4, h = bh & 15;
    const int itA = (TT / 64) - 1 - p;                 // heavy q-tile
    const int itB = p;                                 // light q-tile

    const unsigned short* Kg = K + (size_t)b * TT * TE + h * THS;  // row stride TE
    const unsigned short* Vg = Vt + (size_t)bh * THS * TT;         // [d][t]

    // Q fragments for both segments (A/B MFMA operand layouts coincide)
    const size_t qrA = (size_t)(b * TT + itA * 64 + wl * 16 + l16) * TE + h * THS;
    const size_t qrB = (size_t)(b * TT + itB * 64 + wl * 16 + l16) * TE + h * THS;
    const short8 aqA0 = *(const short8*)&Q[qrA + quad * 8];
    const short8 aqA1 = *(const short8*)&Q[qrA + 32 + quad * 8];
    const short8 aqB0 = *(const short8*)&Q[qrB + quad * 8];
    const short8 aqB1 = *(const short8*)&Q[qrB + 32 + quad * 8];

    const f32x4 fz = {0.f, 0.f, 0.f, 0.f};
    const int srow = lane >> 2;
    const int scol = (((lane & 3) ^ ((srow >> 1) & 3))) * 8;  // swizzled source col
    const int rchunk = (quad ^ ((l16 >> 1) & 3)) * 8;          // swizzled read col

    unsigned short* Sw = S[wk];
    float* Sf = (float*)S;

    auto stageKV = [&](int jt, int it, int buf) {
        const int k0 = (jt > it ? it : jt) * 64;   // clamp dead iterations
        if (wl < 2) {  // waves 0-1 of group: K tile (8 KB)
            #pragma unroll
            for (int j = 0; j < 4; ++j) {
                const int ee = wl * 4 + j;
                const int kk = ee >> 2, r16 = (ee & 3) * 16;
                gload_lds16(Kg + (size_t)(k0 + r16 + srow) * TE + kk * 32 + scol,
                            &Sw[buf * 4096 + ee * 512 + lane * 8]);
            }
        } else {       // waves 2-3 of group: V^T tile (8 KB)
            #pragma unroll
            for (int j = 0; j < 4; ++j) {
                const int ee = (wl - 2) * 4 + j;
                const int kk = ee >> 2, r16 = (ee & 3) * 16;
                gload_lds16(Vg + (size_t)(r16 + srow) * TT + k0 + kk * 32 + scol,
                            &Sw[8192 + buf * 4096 + ee * 512 + lane * 8]);
            }
        }
    };

    int cur = 0;
    const int src0 = ((quad & 1) << 5) + l16;
    const bool hi = quad >= 2;

    auto segment = [&](int it, short8 aq0, short8 aq1, int nextit /* -1 = none */) {
        const int h0 = (it + 2) >> 1;          // ceil((it+1)/2), loop count (both groups)
        const int base = wk ? h0 : 0;
        f32x4 acc_o[4];
        #pragma unroll
        for (int ni = 0; ni < 4; ++ni) acc_o[ni] = fz;
        float lacc = 0.f;
        const int q0 = it * 64;
        const int qg = q0 + wl * 16 + l16;     // this lane's q column (S^T)

        for (int i = 0; i < h0; ++i) {
            const int jt = base + i;
            __syncthreads();                   // buf[cur] staged; buf[cur^1] free
            if (i + 1 < h0) stageKV(base + i + 1, it, cur ^ 1);
            else if (nextit >= 0) stageKV(wk ? ((nextit + 2) >> 1) : 0, nextit, cur ^ 1);

            // S^T = K·Q^T  (Q pre-scaled -> s is already in exp2 domain)
            f32x4 s[4];
            #pragma unroll
            for (int ni = 0; ni < 4; ++ni) {
                short8 kf0 = *(const short8*)&Sw[cur * 4096 + (ni * 16 + l16) * 32 + rchunk];
                short8 kf1 = *(const short8*)&Sw[cur * 4096 + 2048 + (ni * 16 + l16) * 32 + rchunk];
                s[ni] = mfma16(kf0, aq0, fz);
                s[ni] = mfma16(kf1, aq1, s[ni]);
            }

            // softmax weights (fixed max=0), tile-type specialized
            const int k0 = jt * 64;
            float pv[4][4];
            if (jt < it) {                     // full tile: no masking at all
                #pragma unroll
                for (int ni = 0; ni < 4; ++ni)
                    #pragma unroll
                    for (int r = 0; r < 4; ++r) {
                        pv[ni][r] = __builtin_amdgcn_exp2f(s[ni][r]);
                        lacc += pv[ni][r];
                    }
            } else if (jt == it) {             // diagonal: causal select
                #pragma unroll
                for (int ni = 0; ni < 4; ++ni) {
                    const int kpb = k0 + ni * 16 + quad * 4;
                    #pragma unroll
                    for (int r = 0; r < 4; ++r) {
                        float e = __builtin_amdgcn_exp2f(s[ni][r]);
                        pv[ni][r] = (kpb + r > qg) ? 0.f : e;
                        lacc += pv[ni][r];
                    }
                }
            } else {                           // dead padding iteration
                #pragma unroll
                for (int ni = 0; ni < 4; ++ni)
                    #pragma unroll
                    for (int r = 0; r < 4; ++r) pv[ni][r] = 0.f;
            }

            // pack P^T via HW cvt_pk: pd0[t]=(r0,r1), pd1[t]=(r2,r3)
            unsigned int pd0[4], pd1[4];
            #pragma unroll
            for (int t = 0; t < 4; ++t) {
                pd0[t] = cvtpk_bf16(pv[t][0], pv[t][1]);
                pd1[t] = cvtpk_bf16(pv[t][2], pv[t][3]);
            }

            // C->A transform via shuffles (no LDS)
            short8 pf[2];
            #pragma unroll
            for (int c = 0; c < 2; ++c) {
                const int tl = 2 * c, th = 2 * c + 1;
                unsigned d0l = __shfl(pd0[tl], src0),      d0h = __shfl(pd0[th], src0);
                unsigned d1l = __shfl(pd1[tl], src0),      d1h = __shfl(pd1[th], src0);
                unsigned d2l = __shfl(pd0[tl], src0 + 16), d2h = __shfl(pd0[th], src0 + 16);
                unsigned d3l = __shfl(pd1[tl], src0 + 16), d3h = __shfl(pd1[th], src0 + 16);
                union { unsigned u[4]; short8 s8; } pk;
                pk.u[0] = hi ? d0h : d0l;
                pk.u[1] = hi ? d1h : d1l;
                pk.u[2] = hi ? d2h : d2l;
                pk.u[3] = hi ? d3h : d3l;
                pf[c] = pk.s8;
            }

            // O += P·V
            #pragma unroll
            for (int ni = 0; ni < 4; ++ni) {
                short8 v0 = *(const short8*)&Sw[8192 + cur * 4096 + (ni * 16 + l16) * 32 + rchunk];
                short8 v1 = *(const short8*)&Sw[8192 + cur * 4096 + 2048 + (ni * 16 + l16) * 32 + rchunk];
                acc_o[ni] = mfma16(pf[0], v0, acc_o[ni]);
                acc_o[ni] = mfma16(pf[1], v1, acc_o[ni]);
            }
            cur ^= 1;
        }

        // full column sums within group
        lacc += __shfl_xor(lacc, 16);
        lacc += __shfl_xor(lacc, 32);

        // cross-group combine through freed K buffers (buf cur^1 of each group)
        __syncthreads();                        // all reads of freed bufs done
        const int fb = cur ^ 1;
        if (wk == 0) {
            #pragma unroll
            for (int ni = 0; ni < 4; ++ni)
                #pragma unroll
                for (int r = 0; r < 4; ++r) {
                    const int row = wl * 16 + quad * 4 + r;
                    const int idx = row * 64 + ni * 16 + l16;
                    Sf[(idx >> 11) * 8192 + fb * 2048 + (idx & 2047)] = acc_o[ni][r];
                }
            if (quad == 0) L0[wl * 16 + l16] = lacc;
        }
        __syncthreads();
        if (wk == 1) {
            const float lf = lacc + L0[wl * 16 + l16];
            float linv[4];
            #pragma unroll
            for (int r = 0; r < 4; ++r)
                linv[r] = 1.0f / __shfl(lf, quad * 4 + r);
            unsigned short* Og = O + (size_t)(b * TT + q0 + wl * 16 + quad * 4) * TE + h * THS;
            #pragma unroll
            for (int r = 0; r < 4; ++r)
                #pragma unroll
                for (int ni = 0; ni < 4; ++ni) {
                    const int row = wl * 16 + quad * 4 + r;
                    const int idx = row * 64 + ni * 16 + l16;
                    const float o = acc_o[ni][r] + Sf[(idx >> 11) * 8192 + fb * 2048 + (idx & 2047)];
                    Og[(size_t)r * TE + ni * 16 + l16] = f2bf(o * linv[r]);
                }
        }
    };

    // initial stage: each group its own first tile of segment A
    stageKV(wk ? ((itA + 2) >> 1) : 0, itA, 0);
    segment(itA, aqA0, aqA1, itB);   // heavy tile; last iter prefetches B
    segment(itB, aqB0, aqB1, -1);    // light tile
}

// ---------------------------------------------------------------------------
// Orchestration. Workspace (64 MiB):
//   qc,kc,vc,Qb,Kb,Vt,Ob: 7 x 8 MiB bf16; Wqt,Wkt,Wvt,Wpt: 4 x 2 MiB bf16
// ---------------------------------------------------------------------------
extern "C" void kernel_launch(void* const* d_in, const int* in_sizes, int n_in,
                              void* d_out, int out_size, void* d_ws, size_t ws_size,
                              hipStream_t stream) {
    const float* q  = (const float*)d_in[0];
    const float* k  = (const float*)d_in[1];
    const float* v  = (const float*)d_in[2];
    const float* Wq = (const float*)d_in[3];
    const float* Wk = (const float*)d_in[4];
    const float* Wv = (const float*)d_in[5];
    const float* Wp = (const float*)d_in[6];
    float* out = (float*)d_out;

    const size_t se = (size_t)TM * TE;  // 4,194,304
    unsigned short* qc  = (unsigned short*)d_ws;
    unsigned short* kc  = qc + se;
    unsigned short* vc  = kc + se;
    unsigned short* Qb  = vc + se;
    unsigned short* Kb  = Qb + se;
    unsigned short* Vt  = Kb + se;
    unsigned short* Ob  = Vt + se;
    unsigned short* Wqt = Ob + se;
    unsigned short* Wkt = Wqt + (size_t)TE * TE;
    unsigned short* Wvt = Wkt + (size_t)TE * TE;
    unsigned short* Wpt = Wvt + (size_t)TE * TE;

    const int n4 = (int)(se / 4);
    cast3_f32_bf16<<<dim3(n4 / 256, 3), 256, 0, stream>>>(q, k, v, qc, kc, vc, n4);
    transpose_cast_w4<<<dim3(TE / 32, TE / 32, 4), 256, 0, stream>>>(
        Wq, Wk, Wv, Wp, Wqt, Wkt, Wvt, Wpt);

    gemm_qkv<<<dim3(TM / 128, TE / 128, 3), 256, 0, stream>>>(
        qc, kc, vc, Wqt, Wkt, Wvt, Qb, Kb, Vt);

    attn_mfma<<<512, 512, 0, stream>>>(Qb, Kb, Vt, Ob);

    gemm_out<<<dim3(TM / 128, TE / 64), 256, 0, stream>>>(Ob, Wpt, out);
}